// Round 13
// baseline (376.260 us; speedup 1.0000x reference)
//
#include <hip/hip_runtime.h>
#include <hip/hip_bf16.h>
#include <stdint.h>

#define T_TOK 1024
#define HID   1024
#define INT_  4096
#define NE    8

typedef __attribute__((ext_vector_type(4))) float f32x4;
typedef __attribute__((ext_vector_type(8))) short short8;

__device__ int g_tok[NE][T_TOK];
__device__ int g_cnt[NE];

__device__ __forceinline__ uint32_t pack2bf(float a, float b) {
  unsigned short ua = __builtin_bit_cast(unsigned short, (__bf16)a);
  unsigned short ub = __builtin_bit_cast(unsigned short, (__bf16)b);
  return (uint32_t)ua | ((uint32_t)ub << 16);
}

// global_load_lds: per-lane global src, wave-uniform LDS base (HW adds lane*16)
#define GL16(gsrc, ldst)                                                       \
  __builtin_amdgcn_global_load_lds(                                            \
      (const __attribute__((address_space(1))) void*)(gsrc),                   \
      (__attribute__((address_space(3))) void*)(ldst), 16, 0, 0)

// ---------------- Kernel 0: per-expert token compaction ---------------------
__global__ void k0_compact(const int* __restrict__ mask)  // [T_TOK][NE]
{
  const int w    = threadIdx.x >> 6;
  const int lane = threadIdx.x & 63;
  if (w >= NE) return;
  const unsigned long long ltmask = (1ull << lane) - 1ull;
  int base = 0;
  #pragma unroll
  for (int c = 0; c < T_TOK / 64; ++c) {
    const int t = c * 64 + lane;
    const bool pred = mask[t * NE + w] != 0;
    const unsigned long long bal = __ballot(pred);
    if (pred) g_tok[w][base + __popcll(bal & ltmask)] = t;
    base += __popcll(bal);
  }
  if (lane == 0) g_cnt[w] = base;
}

// ---------------- cvt_x: x f32 -> bf16 linear -------------------------------
__global__ void cvt_x(const float* __restrict__ xin, unsigned short* __restrict__ xout)
{
  const int i = (blockIdx.x * 256 + threadIdx.x) * 8;
  f32x4 a = *(const f32x4*)(xin + i);
  f32x4 b = *(const f32x4*)(xin + i + 4);
  uint4 u;
  u.x = pack2bf(a[0], a[1]); u.y = pack2bf(a[2], a[3]);
  u.z = pack2bf(b[0], b[1]); u.w = pack2bf(b[2], b[3]);
  *(uint4*)(xout + i) = u;
}

// ---------------- cvt_T: per-expert [R][C] f32 -> [C][R] bf16 ---------------
// [256 k x 64 n] tiles: coalesced f32x4 reads (256-B segments), padded-LDS
// transpose (store banks exact 2-way = free), 512-B contiguous write runs.
__global__ __launch_bounds__(256)
void cvt_T(const float* __restrict__ in, unsigned short* __restrict__ out,
           int R, int C)
{
  __shared__ float tT[64][257];        // [n][k], pad 1 -> 64.25 KB, 2 blk/CU
  const int e  = blockIdx.z;
  const int c0 = blockIdx.x * 64;
  const int r0 = blockIdx.y * 256;
  const float*    ip = in  + (size_t)e * R * C;
  unsigned short* op = out + (size_t)e * R * C;
  const int t  = threadIdx.x;
  const int rr = t >> 4;               // 0..15
  const int c4 = (t & 15) * 4;
  #pragma unroll
  for (int p = 0; p < 16; ++p) {
    const int row = p * 16 + rr;
    f32x4 v = *(const f32x4*)(ip + (size_t)(r0 + row) * C + c0 + c4);
    tT[c4 + 0][row] = v[0];
    tT[c4 + 1][row] = v[1];
    tT[c4 + 2][row] = v[2];
    tT[c4 + 3][row] = v[3];
  }
  __syncthreads();
  const int c  = t >> 2;               // 0..63
  const int kc = (t & 3) * 64;         // 4 threads cover 256 k = 512 B run
  unsigned short* orow = op + (size_t)(c0 + c) * R + r0 + kc;
  #pragma unroll
  for (int q = 0; q < 8; ++q) {
    const float* s = &tT[c][kc + q * 8];
    uint4 u;
    u.x = pack2bf(s[0], s[1]);
    u.y = pack2bf(s[2], s[3]);
    u.z = pack2bf(s[4], s[5]);
    u.w = pack2bf(s[6], s[7]);
    *(uint4*)(orow + q * 8) = u;
  }
}

// ---------------- Kernel 1: act[e,slot,i] = up * silu(gate) -----------------
// 3-deep GL16 pipeline, counted vmcnt (never drains mid-loop), raw barriers.
// 512 thr (8 waves, 4m x 2n). M=256, N=64 (gate AND up). LDS 144 KB.
// UNCHANGED from R12 (346 us best).
__global__ __launch_bounds__(512, 1)
void k1_gateup(const unsigned short* __restrict__ xb,    // [T][H] bf16
               const unsigned short* __restrict__ wguT,  // [e][8192][1024] bf16
               unsigned short* __restrict__ act)         // [e][T][INT_] bf16
{
  const int e   = blockIdx.z;
  const int cnt = g_cnt[e];
  const int mt  = blockIdx.y;
  const int t0  = mt * 256;
  if (t0 >= cnt) return;

  __shared__ char sA [3][256 * 128];   // 96 KB
  __shared__ char sBg[3][64 * 128];    // 24 KB
  __shared__ char sBu[3][64 * 128];    // 24 KB

  const int nt   = blockIdx.x;         // 0..63
  const int tid  = threadIdx.x;
  const int lane = tid & 63;
  const int wv   = tid >> 6;           // 0..7
  const int wm   = (wv >> 1) * 64;     // 0/64/128/192
  const int wn   = (wv & 1) * 32;      // 0/32
  const int n0   = nt * 64;

  const unsigned short* wg = wguT + (size_t)e * 8192 * HID + (size_t)n0 * HID;
  const unsigned short* wu = wg + (size_t)4096 * HID;

  f32x4 accg[4][2], accu[4][2];
  #pragma unroll
  for (int i = 0; i < 4; ++i)
    #pragma unroll
    for (int j = 0; j < 2; ++j) {
      accg[i][j] = (f32x4){0.f, 0.f, 0.f, 0.f};
      accu[i][j] = (f32x4){0.f, 0.f, 0.f, 0.f};
    }

  const int drow  = lane >> 3;                    // 0..7
  const int dchk8 = (((lane & 7) ^ drow) << 3);   // source-XOR chunk (rule #21)

  int tokA[4];
  #pragma unroll
  for (int s = 0; s < 4; ++s)
    tokA[s] = g_tok[e][t0 + (s * 8 + wv) * 8 + drow];

#define K1_STAGE(B, T_)                                                        \
  do {                                                                         \
    const int kt_ = (T_) * 64;                                                 \
    _Pragma("unroll")                                                          \
    for (int s_ = 0; s_ < 4; ++s_) {                                           \
      const int rb_ = (s_ * 8 + wv) * 8;                                       \
      GL16(xb + (size_t)tokA[s_] * HID + kt_ + dchk8, sA[B] + rb_ * 128);      \
    }                                                                          \
    {                                                                          \
      const int rb_ = wv * 8;                                                  \
      GL16(wg + (size_t)(rb_ + drow) * HID + kt_ + dchk8, sBg[B] + rb_ * 128); \
      GL16(wu + (size_t)(rb_ + drow) * HID + kt_ + dchk8, sBu[B] + rb_ * 128); \
    }                                                                          \
  } while (0)

  K1_STAGE(0, 0);
  K1_STAGE(1, 1);

  #pragma unroll
  for (int t = 0; t < 16; ++t) {
    if (t + 2 < 16) K1_STAGE((t + 2) % 3, t + 2);
    if (t < 14)      asm volatile("s_waitcnt vmcnt(12)" ::: "memory");
    else if (t == 14) asm volatile("s_waitcnt vmcnt(6)" ::: "memory");
    else              asm volatile("s_waitcnt vmcnt(0)" ::: "memory");
    __builtin_amdgcn_s_barrier();
    __builtin_amdgcn_sched_barrier(0);   // pin ds_reads below the barrier
    const char* cA  = sA [t % 3];
    const char* cBg = sBg[t % 3];
    const char* cBu = sBu[t % 3];
    #pragma unroll
    for (int ks = 0; ks < 2; ++ks) {
      const int kfb = ks * 64 + ((lane >> 4) << 4);
      short8 af[4], bg[2], bu[2];
      #pragma unroll
      for (int i = 0; i < 4; ++i) {
        const int r = wm + i * 16 + (lane & 15);
        af[i] = *(const short8*)(cA + r * 128 + (kfb ^ ((r & 7) << 4)));
      }
      #pragma unroll
      for (int j = 0; j < 2; ++j) {
        const int r = wn + j * 16 + (lane & 15);
        const int off = r * 128 + (kfb ^ ((r & 7) << 4));
        bg[j] = *(const short8*)(cBg + off);
        bu[j] = *(const short8*)(cBu + off);
      }
      #pragma unroll
      for (int i = 0; i < 4; ++i)
        #pragma unroll
        for (int j = 0; j < 2; ++j) {
          accg[i][j] = __builtin_amdgcn_mfma_f32_16x16x32_bf16(af[i], bg[j], accg[i][j], 0, 0, 0);
          accu[i][j] = __builtin_amdgcn_mfma_f32_16x16x32_bf16(af[i], bu[j], accu[i][j], 0, 0, 0);
        }
    }
    __builtin_amdgcn_s_barrier();        // protect buf (re-staged next iter)
  }
#undef K1_STAGE

  unsigned short* ab = act + (size_t)e * T_TOK * INT_;
  #pragma unroll
  for (int i = 0; i < 4; ++i) {
    #pragma unroll
    for (int r = 0; r < 4; ++r) {
      const int slot = t0 + wm + i * 16 + ((lane >> 4) << 2) + r;
      if (slot < cnt) {
        #pragma unroll
        for (int j = 0; j < 2; ++j) {
          const int col = n0 + wn + j * 16 + (lane & 15);
          const float g = accg[i][j][r];
          const float u = accu[i][j][r];
          const float s = u * g / (1.f + __expf(-g));
          ab[(size_t)slot * INT_ + col] = __builtin_bit_cast(unsigned short, (__bf16)s);
        }
      }
    }
  }
}

// ---------------- Kernel 2: out += act[e] @ wdT[e]^T ------------------------
// 256 thr (4 waves 2x2), M=128 N=128, K split 4-way, 2-buf counted vmcnt(8).
// UNCHANGED from R12.
__global__ __launch_bounds__(256, 2)
void k2_down(const unsigned short* __restrict__ act,   // [e][T][INT_] bf16
             const unsigned short* __restrict__ wdT,   // [e][1024][4096] bf16
             float* __restrict__ out)
{
  const int e   = blockIdx.z;
  const int cnt = g_cnt[e];
  const int mt  = blockIdx.y >> 2;
  const int ks4 = blockIdx.y & 3;
  const int t0  = mt * 128;
  if (t0 >= cnt) return;

  __shared__ char sA[2][128 * 128];    // 32 KB
  __shared__ char sB[2][128 * 128];    // 32 KB

  const int nt   = blockIdx.x;
  const int tid  = threadIdx.x;
  const int lane = tid & 63;
  const int wv   = tid >> 6;           // 0..3
  const int wm   = (wv >> 1) * 64;
  const int wn   = (wv & 1) * 64;
  const int n0   = nt * 128;

  const unsigned short* ab = act + (size_t)e * T_TOK * INT_;
  const unsigned short* wb = wdT + (size_t)e * HID * INT_ + (size_t)n0 * INT_;

  f32x4 acc[4][4];
  #pragma unroll
  for (int i = 0; i < 4; ++i)
    #pragma unroll
    for (int j = 0; j < 4; ++j) acc[i][j] = (f32x4){0.f, 0.f, 0.f, 0.f};

  const int drow  = lane >> 3;
  const int dchk8 = (((lane & 7) ^ drow) << 3);
  const int kbeg  = ks4 * (INT_ / 4);

#define K2_STAGE(B, KT)                                                        \
  do {                                                                         \
    _Pragma("unroll")                                                          \
    for (int s_ = 0; s_ < 4; ++s_) {                                           \
      const int rb_ = (s_ * 4 + wv) * 8;                                       \
      GL16(ab + (size_t)(t0 + rb_ + drow) * INT_ + (KT) + dchk8, sA[B] + rb_ * 128); \
      GL16(wb + (size_t)(rb_ + drow) * INT_ + (KT) + dchk8, sB[B] + rb_ * 128);      \
    }                                                                          \
  } while (0)

  K2_STAGE(0, kbeg);

  #pragma unroll
  for (int t = 0; t < 16; ++t) {
    const int cur = t & 1;
    if (t < 15) K2_STAGE(cur ^ 1, kbeg + (t + 1) * 64);
    if (t < 15) asm volatile("s_waitcnt vmcnt(8)" ::: "memory");
    else        asm volatile("s_waitcnt vmcnt(0)" ::: "memory");
    __builtin_amdgcn_s_barrier();
    __builtin_amdgcn_sched_barrier(0);
    #pragma unroll
    for (int ks = 0; ks < 2; ++ks) {
      const int kfb = ks * 64 + ((lane >> 4) << 4);
      short8 af[4], bf[4];
      #pragma unroll
      for (int i = 0; i < 4; ++i) {
        const int r = wm + i * 16 + (lane & 15);
        af[i] = *(const short8*)(sA[cur] + r * 128 + (kfb ^ ((r & 7) << 4)));
      }
      #pragma unroll
      for (int j = 0; j < 4; ++j) {
        const int r = wn + j * 16 + (lane & 15);
        bf[j] = *(const short8*)(sB[cur] + r * 128 + (kfb ^ ((r & 7) << 4)));
      }
      #pragma unroll
      for (int i = 0; i < 4; ++i)
        #pragma unroll
        for (int j = 0; j < 4; ++j)
          acc[i][j] = __builtin_amdgcn_mfma_f32_16x16x32_bf16(af[i], bf[j], acc[i][j], 0, 0, 0);
    }
    __builtin_amdgcn_s_barrier();
  }
#undef K2_STAGE

  #pragma unroll
  for (int i = 0; i < 4; ++i) {
    #pragma unroll
    for (int r = 0; r < 4; ++r) {
      const int slot = t0 + wm + i * 16 + ((lane >> 4) << 2) + r;
      if (slot < cnt) {
        const int token = g_tok[e][slot];
        #pragma unroll
        for (int j = 0; j < 4; ++j) {
          const int col = n0 + wn + j * 16 + (lane & 15);
          atomicAdd(out + (size_t)token * HID + col, acc[i][j][r]);
        }
      }
    }
  }
}

extern "C" void kernel_launch(void* const* d_in, const int* in_sizes, int n_in,
                              void* d_out, int out_size, void* d_ws, size_t ws_size,
                              hipStream_t stream) {
  const float* x   = (const float*)d_in[0];
  const int*   idx = (const int*)d_in[1];
  const float* wgu = (const float*)d_in[2];
  const float* wd  = (const float*)d_in[3];
  float* out = (float*)d_out;

  // workspace layout (bytes):
  // act   @ 0          : 67,108,864
  // xb16  @ 67108864   :  2,097,152
  // wguT  @ 69206016   : 134,217,728
  // wdT   @ 203423744  : 67,108,864   (total ~258 MiB)
  char* ws = (char*)d_ws;
  unsigned short* act  = (unsigned short*)(ws);
  unsigned short* xb16 = (unsigned short*)(ws + 67108864);
  unsigned short* wguT = (unsigned short*)(ws + 69206016);
  unsigned short* wdT  = (unsigned short*)(ws + 203423744);

  hipMemsetAsync(d_out, 0, (size_t)out_size * sizeof(float), stream);

  k0_compact<<<1, 512, 0, stream>>>(idx);
  cvt_x<<<T_TOK * HID / (256 * 8), 256, 0, stream>>>(x, xb16);
  cvt_T<<<dim3(8192 / 64, 1024 / 256, NE), 256, 0, stream>>>(wgu, wguT, 1024, 8192);
  cvt_T<<<dim3(1024 / 64, 4096 / 256, NE), 256, 0, stream>>>(wd, wdT, 4096, 1024);

  dim3 g1(INT_ / 64, T_TOK / 256, NE);         // (64, 4, 8)
  k1_gateup<<<g1, dim3(512), 0, stream>>>(xb16, wguT, act);

  dim3 g2(HID / 128, (T_TOK / 128) * 4, NE);   // (8, 32, 8) — y = mt*4|ks
  k2_down<<<g2, dim3(256), 0, stream>>>(act, wdT, out);
}

// Round 14
// 354.877 us; speedup vs baseline: 1.0603x; 1.0603x over previous
//
#include <hip/hip_runtime.h>
#include <hip/hip_bf16.h>
#include <stdint.h>

#define T_TOK 1024
#define HID   1024
#define INT_  4096
#define NE    8

typedef __attribute__((ext_vector_type(4))) float f32x4;
typedef __attribute__((ext_vector_type(8))) short short8;

__device__ int g_tok[NE][T_TOK];
__device__ int g_cnt[NE];

__device__ __forceinline__ uint32_t pack2bf(float a, float b) {
  unsigned short ua = __builtin_bit_cast(unsigned short, (__bf16)a);
  unsigned short ub = __builtin_bit_cast(unsigned short, (__bf16)b);
  return (uint32_t)ua | ((uint32_t)ub << 16);
}

// global_load_lds: per-lane global src, wave-uniform LDS base (HW adds lane*16)
#define GL16(gsrc, ldst)                                                       \
  __builtin_amdgcn_global_load_lds(                                            \
      (const __attribute__((address_space(1))) void*)(gsrc),                   \
      (__attribute__((address_space(3))) void*)(ldst), 16, 0, 0)

// ---------------- Kernel 0: per-expert token compaction ---------------------
__global__ void k0_compact(const int* __restrict__ mask)  // [T_TOK][NE]
{
  const int w    = threadIdx.x >> 6;
  const int lane = threadIdx.x & 63;
  if (w >= NE) return;
  const unsigned long long ltmask = (1ull << lane) - 1ull;
  int base = 0;
  #pragma unroll
  for (int c = 0; c < T_TOK / 64; ++c) {
    const int t = c * 64 + lane;
    const bool pred = mask[t * NE + w] != 0;
    const unsigned long long bal = __ballot(pred);
    if (pred) g_tok[w][base + __popcll(bal & ltmask)] = t;
    base += __popcll(bal);
  }
  if (lane == 0) g_cnt[w] = base;
}

// ---------------- cvt_x: x f32 -> bf16 linear -------------------------------
__global__ void cvt_x(const float* __restrict__ xin, unsigned short* __restrict__ xout)
{
  const int i = (blockIdx.x * 256 + threadIdx.x) * 8;
  f32x4 a = *(const f32x4*)(xin + i);
  f32x4 b = *(const f32x4*)(xin + i + 4);
  uint4 u;
  u.x = pack2bf(a[0], a[1]); u.y = pack2bf(a[2], a[3]);
  u.z = pack2bf(b[0], b[1]); u.w = pack2bf(b[2], b[3]);
  *(uint4*)(xout + i) = u;
}

// ---------------- cvt_T: per-expert [R][C] f32 -> [C][R] bf16 ---------------
// R12 version (64x64 tile, 16.6 KB LDS, high occupancy) — R13's 256-row tile
// regressed via occupancy loss; reverted.
__global__ void cvt_T(const float* __restrict__ in, unsigned short* __restrict__ out,
                      int R, int C)
{
  __shared__ float tile[64][65];
  const int e  = blockIdx.z;
  const int c0 = blockIdx.x * 64;
  const int r0 = blockIdx.y * 64;
  const float*    ip = in  + (size_t)e * R * C;
  unsigned short* op = out + (size_t)e * R * C;
  const int t  = threadIdx.x;
  const int rr = t >> 4, c4 = (t & 15) * 4;
  #pragma unroll
  for (int s = 0; s < 4; ++s) {
    f32x4 v = *(const f32x4*)(ip + (size_t)(r0 + s * 16 + rr) * C + c0 + c4);
    tile[s * 16 + rr][c4 + 0] = v[0];
    tile[s * 16 + rr][c4 + 1] = v[1];
    tile[s * 16 + rr][c4 + 2] = v[2];
    tile[s * 16 + rr][c4 + 3] = v[3];
  }
  __syncthreads();
  const int c = t >> 2, rs = (t & 3) * 16;
  uint4 u0, u1;
  u0.x = pack2bf(tile[rs + 0][c],  tile[rs + 1][c]);
  u0.y = pack2bf(tile[rs + 2][c],  tile[rs + 3][c]);
  u0.z = pack2bf(tile[rs + 4][c],  tile[rs + 5][c]);
  u0.w = pack2bf(tile[rs + 6][c],  tile[rs + 7][c]);
  u1.x = pack2bf(tile[rs + 8][c],  tile[rs + 9][c]);
  u1.y = pack2bf(tile[rs + 10][c], tile[rs + 11][c]);
  u1.z = pack2bf(tile[rs + 12][c], tile[rs + 13][c]);
  u1.w = pack2bf(tile[rs + 14][c], tile[rs + 15][c]);
  unsigned short* orow = op + (size_t)(c0 + c) * R + r0 + rs;
  *(uint4*)(orow)     = u0;
  *(uint4*)(orow + 8) = u1;
}

// ---------------- Kernel 1: act[e,slot,i] = up * silu(gate) -----------------
// R12 structure (3-deep GL16 pipeline, counted vmcnt, raw barriers)
// + T5: s_setprio(1) around the MFMA cluster (role-split waves -> arbitrable).
__global__ __launch_bounds__(512, 1)
void k1_gateup(const unsigned short* __restrict__ xb,    // [T][H] bf16
               const unsigned short* __restrict__ wguT,  // [e][8192][1024] bf16
               unsigned short* __restrict__ act)         // [e][T][INT_] bf16
{
  const int e   = blockIdx.z;
  const int cnt = g_cnt[e];
  const int mt  = blockIdx.y;
  const int t0  = mt * 256;
  if (t0 >= cnt) return;

  __shared__ char sA [3][256 * 128];   // 96 KB
  __shared__ char sBg[3][64 * 128];    // 24 KB
  __shared__ char sBu[3][64 * 128];    // 24 KB

  const int nt   = blockIdx.x;         // 0..63
  const int tid  = threadIdx.x;
  const int lane = tid & 63;
  const int wv   = tid >> 6;           // 0..7
  const int wm   = (wv >> 1) * 64;     // 0/64/128/192
  const int wn   = (wv & 1) * 32;      // 0/32
  const int n0   = nt * 64;

  const unsigned short* wg = wguT + (size_t)e * 8192 * HID + (size_t)n0 * HID;
  const unsigned short* wu = wg + (size_t)4096 * HID;

  f32x4 accg[4][2], accu[4][2];
  #pragma unroll
  for (int i = 0; i < 4; ++i)
    #pragma unroll
    for (int j = 0; j < 2; ++j) {
      accg[i][j] = (f32x4){0.f, 0.f, 0.f, 0.f};
      accu[i][j] = (f32x4){0.f, 0.f, 0.f, 0.f};
    }

  const int drow  = lane >> 3;                    // 0..7
  const int dchk8 = (((lane & 7) ^ drow) << 3);   // source-XOR chunk (rule #21)

  int tokA[4];
  #pragma unroll
  for (int s = 0; s < 4; ++s)
    tokA[s] = g_tok[e][t0 + (s * 8 + wv) * 8 + drow];

#define K1_STAGE(B, T_)                                                        \
  do {                                                                         \
    const int kt_ = (T_) * 64;                                                 \
    _Pragma("unroll")                                                          \
    for (int s_ = 0; s_ < 4; ++s_) {                                           \
      const int rb_ = (s_ * 8 + wv) * 8;                                       \
      GL16(xb + (size_t)tokA[s_] * HID + kt_ + dchk8, sA[B] + rb_ * 128);      \
    }                                                                          \
    {                                                                          \
      const int rb_ = wv * 8;                                                  \
      GL16(wg + (size_t)(rb_ + drow) * HID + kt_ + dchk8, sBg[B] + rb_ * 128); \
      GL16(wu + (size_t)(rb_ + drow) * HID + kt_ + dchk8, sBu[B] + rb_ * 128); \
    }                                                                          \
  } while (0)

  K1_STAGE(0, 0);
  K1_STAGE(1, 1);

  #pragma unroll
  for (int t = 0; t < 16; ++t) {
    if (t + 2 < 16) K1_STAGE((t + 2) % 3, t + 2);
    if (t < 14)      asm volatile("s_waitcnt vmcnt(12)" ::: "memory");
    else if (t == 14) asm volatile("s_waitcnt vmcnt(6)" ::: "memory");
    else              asm volatile("s_waitcnt vmcnt(0)" ::: "memory");
    __builtin_amdgcn_s_barrier();
    __builtin_amdgcn_sched_barrier(0);   // pin ds_reads below the barrier
    const char* cA  = sA [t % 3];
    const char* cBg = sBg[t % 3];
    const char* cBu = sBu[t % 3];
    __builtin_amdgcn_s_setprio(1);       // T5: favor compute-phase waves
    #pragma unroll
    for (int ks = 0; ks < 2; ++ks) {
      const int kfb = ks * 64 + ((lane >> 4) << 4);
      short8 af[4], bg[2], bu[2];
      #pragma unroll
      for (int i = 0; i < 4; ++i) {
        const int r = wm + i * 16 + (lane & 15);
        af[i] = *(const short8*)(cA + r * 128 + (kfb ^ ((r & 7) << 4)));
      }
      #pragma unroll
      for (int j = 0; j < 2; ++j) {
        const int r = wn + j * 16 + (lane & 15);
        const int off = r * 128 + (kfb ^ ((r & 7) << 4));
        bg[j] = *(const short8*)(cBg + off);
        bu[j] = *(const short8*)(cBu + off);
      }
      #pragma unroll
      for (int i = 0; i < 4; ++i)
        #pragma unroll
        for (int j = 0; j < 2; ++j) {
          accg[i][j] = __builtin_amdgcn_mfma_f32_16x16x32_bf16(af[i], bg[j], accg[i][j], 0, 0, 0);
          accu[i][j] = __builtin_amdgcn_mfma_f32_16x16x32_bf16(af[i], bu[j], accu[i][j], 0, 0, 0);
        }
    }
    __builtin_amdgcn_s_setprio(0);
    __builtin_amdgcn_s_barrier();        // protect buf (re-staged next iter)
  }
#undef K1_STAGE

  unsigned short* ab = act + (size_t)e * T_TOK * INT_;
  #pragma unroll
  for (int i = 0; i < 4; ++i) {
    #pragma unroll
    for (int r = 0; r < 4; ++r) {
      const int slot = t0 + wm + i * 16 + ((lane >> 4) << 2) + r;
      if (slot < cnt) {
        #pragma unroll
        for (int j = 0; j < 2; ++j) {
          const int col = n0 + wn + j * 16 + (lane & 15);
          const float g = accg[i][j][r];
          const float u = accu[i][j][r];
          const float s = u * g / (1.f + __expf(-g));
          ab[(size_t)slot * INT_ + col] = __builtin_bit_cast(unsigned short, (__bf16)s);
        }
      }
    }
  }
}

// ---------------- Kernel 2: out += act[e] @ wdT[e]^T ------------------------
// R12 structure + T5 setprio around MFMA cluster.
__global__ __launch_bounds__(256, 2)
void k2_down(const unsigned short* __restrict__ act,   // [e][T][INT_] bf16
             const unsigned short* __restrict__ wdT,   // [e][1024][4096] bf16
             float* __restrict__ out)
{
  const int e   = blockIdx.z;
  const int cnt = g_cnt[e];
  const int mt  = blockIdx.y >> 2;
  const int ks4 = blockIdx.y & 3;
  const int t0  = mt * 128;
  if (t0 >= cnt) return;

  __shared__ char sA[2][128 * 128];    // 32 KB
  __shared__ char sB[2][128 * 128];    // 32 KB

  const int nt   = blockIdx.x;
  const int tid  = threadIdx.x;
  const int lane = tid & 63;
  const int wv   = tid >> 6;           // 0..3
  const int wm   = (wv >> 1) * 64;
  const int wn   = (wv & 1) * 64;
  const int n0   = nt * 128;

  const unsigned short* ab = act + (size_t)e * T_TOK * INT_;
  const unsigned short* wb = wdT + (size_t)e * HID * INT_ + (size_t)n0 * INT_;

  f32x4 acc[4][4];
  #pragma unroll
  for (int i = 0; i < 4; ++i)
    #pragma unroll
    for (int j = 0; j < 4; ++j) acc[i][j] = (f32x4){0.f, 0.f, 0.f, 0.f};

  const int drow  = lane >> 3;
  const int dchk8 = (((lane & 7) ^ drow) << 3);
  const int kbeg  = ks4 * (INT_ / 4);

#define K2_STAGE(B, KT)                                                        \
  do {                                                                         \
    _Pragma("unroll")                                                          \
    for (int s_ = 0; s_ < 4; ++s_) {                                           \
      const int rb_ = (s_ * 4 + wv) * 8;                                       \
      GL16(ab + (size_t)(t0 + rb_ + drow) * INT_ + (KT) + dchk8, sA[B] + rb_ * 128); \
      GL16(wb + (size_t)(rb_ + drow) * INT_ + (KT) + dchk8, sB[B] + rb_ * 128);      \
    }                                                                          \
  } while (0)

  K2_STAGE(0, kbeg);

  #pragma unroll
  for (int t = 0; t < 16; ++t) {
    const int cur = t & 1;
    if (t < 15) K2_STAGE(cur ^ 1, kbeg + (t + 1) * 64);
    if (t < 15) asm volatile("s_waitcnt vmcnt(8)" ::: "memory");
    else        asm volatile("s_waitcnt vmcnt(0)" ::: "memory");
    __builtin_amdgcn_s_barrier();
    __builtin_amdgcn_sched_barrier(0);
    __builtin_amdgcn_s_setprio(1);
    #pragma unroll
    for (int ks = 0; ks < 2; ++ks) {
      const int kfb = ks * 64 + ((lane >> 4) << 4);
      short8 af[4], bf[4];
      #pragma unroll
      for (int i = 0; i < 4; ++i) {
        const int r = wm + i * 16 + (lane & 15);
        af[i] = *(const short8*)(sA[cur] + r * 128 + (kfb ^ ((r & 7) << 4)));
      }
      #pragma unroll
      for (int j = 0; j < 4; ++j) {
        const int r = wn + j * 16 + (lane & 15);
        bf[j] = *(const short8*)(sB[cur] + r * 128 + (kfb ^ ((r & 7) << 4)));
      }
      #pragma unroll
      for (int i = 0; i < 4; ++i)
        #pragma unroll
        for (int j = 0; j < 4; ++j)
          acc[i][j] = __builtin_amdgcn_mfma_f32_16x16x32_bf16(af[i], bf[j], acc[i][j], 0, 0, 0);
    }
    __builtin_amdgcn_s_setprio(0);
    __builtin_amdgcn_s_barrier();
  }
#undef K2_STAGE

  #pragma unroll
  for (int i = 0; i < 4; ++i) {
    #pragma unroll
    for (int r = 0; r < 4; ++r) {
      const int slot = t0 + wm + i * 16 + ((lane >> 4) << 2) + r;
      if (slot < cnt) {
        const int token = g_tok[e][slot];
        #pragma unroll
        for (int j = 0; j < 4; ++j) {
          const int col = n0 + wn + j * 16 + (lane & 15);
          atomicAdd(out + (size_t)token * HID + col, acc[i][j][r]);
        }
      }
    }
  }
}

extern "C" void kernel_launch(void* const* d_in, const int* in_sizes, int n_in,
                              void* d_out, int out_size, void* d_ws, size_t ws_size,
                              hipStream_t stream) {
  const float* x   = (const float*)d_in[0];
  const int*   idx = (const int*)d_in[1];
  const float* wgu = (const float*)d_in[2];
  const float* wd  = (const float*)d_in[3];
  float* out = (float*)d_out;

  // workspace layout (bytes):
  // act   @ 0          : 67,108,864
  // xb16  @ 67108864   :  2,097,152
  // wguT  @ 69206016   : 134,217,728
  // wdT   @ 203423744  : 67,108,864   (total ~258 MiB)
  char* ws = (char*)d_ws;
  unsigned short* act  = (unsigned short*)(ws);
  unsigned short* xb16 = (unsigned short*)(ws + 67108864);
  unsigned short* wguT = (unsigned short*)(ws + 69206016);
  unsigned short* wdT  = (unsigned short*)(ws + 203423744);

  hipMemsetAsync(d_out, 0, (size_t)out_size * sizeof(float), stream);

  k0_compact<<<1, 512, 0, stream>>>(idx);
  cvt_x<<<T_TOK * HID / (256 * 8), 256, 0, stream>>>(x, xb16);
  cvt_T<<<dim3(8192 / 64, 1024 / 64, NE), 256, 0, stream>>>(wgu, wguT, 1024, 8192);
  cvt_T<<<dim3(1024 / 64, 4096 / 64, NE), 256, 0, stream>>>(wd, wdT, 4096, 1024);

  dim3 g1(INT_ / 64, T_TOK / 256, NE);         // (64, 4, 8)
  k1_gateup<<<g1, dim3(512), 0, stream>>>(xb16, wguT, act);

  dim3 g2(HID / 128, (T_TOK / 128) * 4, NE);   // (8, 32, 8) — y = mt*4|ks
  k2_down<<<g2, dim3(256), 0, stream>>>(act, wdT, out);
}

// Round 15
// 334.061 us; speedup vs baseline: 1.1263x; 1.0623x over previous
//
#include <hip/hip_runtime.h>
#include <hip/hip_bf16.h>
#include <stdint.h>

#define T_TOK 1024
#define HID   1024
#define INT_  4096
#define NE    8

typedef __attribute__((ext_vector_type(4))) float f32x4;
typedef __attribute__((ext_vector_type(8))) short short8;

__device__ int g_tok[NE][T_TOK];
__device__ int g_cnt[NE];

__device__ __forceinline__ uint32_t pack2bf(float a, float b) {
  unsigned short ua = __builtin_bit_cast(unsigned short, (__bf16)a);
  unsigned short ub = __builtin_bit_cast(unsigned short, (__bf16)b);
  return (uint32_t)ua | ((uint32_t)ub << 16);
}

// global_load_lds: per-lane global src, wave-uniform LDS base (HW adds lane*16)
#define GL16(gsrc, ldst)                                                       \
  __builtin_amdgcn_global_load_lds(                                            \
      (const __attribute__((address_space(1))) void*)(gsrc),                   \
      (__attribute__((address_space(3))) void*)(ldst), 16, 0, 0)

// ---------------- Kernel 0: per-expert token compaction ---------------------
__global__ void k0_compact(const int* __restrict__ mask)  // [T_TOK][NE]
{
  const int w    = threadIdx.x >> 6;
  const int lane = threadIdx.x & 63;
  if (w >= NE) return;
  const unsigned long long ltmask = (1ull << lane) - 1ull;
  int base = 0;
  #pragma unroll
  for (int c = 0; c < T_TOK / 64; ++c) {
    const int t = c * 64 + lane;
    const bool pred = mask[t * NE + w] != 0;
    const unsigned long long bal = __ballot(pred);
    if (pred) g_tok[w][base + __popcll(bal & ltmask)] = t;
    base += __popcll(bal);
  }
  if (lane == 0) g_cnt[w] = base;
}

// ---------------- cvt_x: x f32 -> bf16 linear -------------------------------
__global__ void cvt_x(const float* __restrict__ xin, unsigned short* __restrict__ xout)
{
  const int i = (blockIdx.x * 256 + threadIdx.x) * 8;
  f32x4 a = *(const f32x4*)(xin + i);
  f32x4 b = *(const f32x4*)(xin + i + 4);
  uint4 u;
  u.x = pack2bf(a[0], a[1]); u.y = pack2bf(a[2], a[3]);
  u.z = pack2bf(b[0], b[1]); u.w = pack2bf(b[2], b[3]);
  *(uint4*)(xout + i) = u;
}

// ---------------- cvt_T: per-expert [R][C] f32 -> [C][R] bf16 ---------------
// R12 version (64x64 tile, 16.6 KB LDS, high occupancy).
__global__ void cvt_T(const float* __restrict__ in, unsigned short* __restrict__ out,
                      int R, int C)
{
  __shared__ float tile[64][65];
  const int e  = blockIdx.z;
  const int c0 = blockIdx.x * 64;
  const int r0 = blockIdx.y * 64;
  const float*    ip = in  + (size_t)e * R * C;
  unsigned short* op = out + (size_t)e * R * C;
  const int t  = threadIdx.x;
  const int rr = t >> 4, c4 = (t & 15) * 4;
  #pragma unroll
  for (int s = 0; s < 4; ++s) {
    f32x4 v = *(const f32x4*)(ip + (size_t)(r0 + s * 16 + rr) * C + c0 + c4);
    tile[s * 16 + rr][c4 + 0] = v[0];
    tile[s * 16 + rr][c4 + 1] = v[1];
    tile[s * 16 + rr][c4 + 2] = v[2];
    tile[s * 16 + rr][c4 + 3] = v[3];
  }
  __syncthreads();
  const int c = t >> 2, rs = (t & 3) * 16;
  uint4 u0, u1;
  u0.x = pack2bf(tile[rs + 0][c],  tile[rs + 1][c]);
  u0.y = pack2bf(tile[rs + 2][c],  tile[rs + 3][c]);
  u0.z = pack2bf(tile[rs + 4][c],  tile[rs + 5][c]);
  u0.w = pack2bf(tile[rs + 6][c],  tile[rs + 7][c]);
  u1.x = pack2bf(tile[rs + 8][c],  tile[rs + 9][c]);
  u1.y = pack2bf(tile[rs + 10][c], tile[rs + 11][c]);
  u1.z = pack2bf(tile[rs + 12][c], tile[rs + 13][c]);
  u1.w = pack2bf(tile[rs + 14][c], tile[rs + 15][c]);
  unsigned short* orow = op + (size_t)(c0 + c) * R + r0 + rs;
  *(uint4*)(orow)     = u0;
  *(uint4*)(orow + 8) = u1;
}

// ---------------- Kernel 1: act[e,slot,i] = up * silu(gate) -----------------
// k2-clone config: 256 thr (4 waves 2m x 2n), M=128, N=64(g)+64(u), BK=64,
// 2-buf 64 KB LDS -> 2 blocks/CU, counted vmcnt(8). 8 GL16/thread/stage.
__global__ __launch_bounds__(256, 2)
void k1_gateup(const unsigned short* __restrict__ xb,    // [T][H] bf16
               const unsigned short* __restrict__ wguT,  // [e][8192][1024] bf16
               unsigned short* __restrict__ act)         // [e][T][INT_] bf16
{
  const int e   = blockIdx.z;
  const int cnt = g_cnt[e];
  const int mt  = blockIdx.y;
  const int t0  = mt * 128;
  if (t0 >= cnt) return;

  __shared__ char sA [2][128 * 128];   // 32 KB
  __shared__ char sBg[2][64 * 128];    // 16 KB
  __shared__ char sBu[2][64 * 128];    // 16 KB

  const int nt   = blockIdx.x;         // 0..63
  const int tid  = threadIdx.x;
  const int lane = tid & 63;
  const int wv   = tid >> 6;           // 0..3
  const int wm   = (wv >> 1) * 64;     // 0/64
  const int wn   = (wv & 1) * 32;      // 0/32
  const int n0   = nt * 64;

  const unsigned short* wg = wguT + (size_t)e * 8192 * HID + (size_t)n0 * HID;
  const unsigned short* wu = wg + (size_t)4096 * HID;

  f32x4 accg[4][2], accu[4][2];
  #pragma unroll
  for (int i = 0; i < 4; ++i)
    #pragma unroll
    for (int j = 0; j < 2; ++j) {
      accg[i][j] = (f32x4){0.f, 0.f, 0.f, 0.f};
      accu[i][j] = (f32x4){0.f, 0.f, 0.f, 0.f};
    }

  const int drow  = lane >> 3;                    // 0..7
  const int dchk8 = (((lane & 7) ^ drow) << 3);   // source-XOR chunk (rule #21)

  int tokA[4];
  #pragma unroll
  for (int s = 0; s < 4; ++s)
    tokA[s] = g_tok[e][t0 + (s * 4 + wv) * 8 + drow];

#define K1_STAGE(B, T_)                                                        \
  do {                                                                         \
    const int kt_ = (T_) * 64;                                                 \
    _Pragma("unroll")                                                          \
    for (int s_ = 0; s_ < 4; ++s_) {                                           \
      const int rb_ = (s_ * 4 + wv) * 8;                                       \
      GL16(xb + (size_t)tokA[s_] * HID + kt_ + dchk8, sA[B] + rb_ * 128);      \
    }                                                                          \
    _Pragma("unroll")                                                          \
    for (int s_ = 0; s_ < 2; ++s_) {                                           \
      const int rb_ = (s_ * 4 + wv) * 8;                                       \
      GL16(wg + (size_t)(rb_ + drow) * HID + kt_ + dchk8, sBg[B] + rb_ * 128); \
      GL16(wu + (size_t)(rb_ + drow) * HID + kt_ + dchk8, sBu[B] + rb_ * 128); \
    }                                                                          \
  } while (0)

  K1_STAGE(0, 0);

  #pragma unroll
  for (int t = 0; t < 16; ++t) {
    const int cur = t & 1;
    if (t < 15) K1_STAGE(cur ^ 1, t + 1);
    if (t < 15) asm volatile("s_waitcnt vmcnt(8)" ::: "memory");
    else        asm volatile("s_waitcnt vmcnt(0)" ::: "memory");
    __builtin_amdgcn_s_barrier();
    __builtin_amdgcn_sched_barrier(0);
    #pragma unroll
    for (int ks = 0; ks < 2; ++ks) {
      const int kfb = ks * 64 + ((lane >> 4) << 4);
      short8 af[4], bg[2], bu[2];
      #pragma unroll
      for (int i = 0; i < 4; ++i) {
        const int r = wm + i * 16 + (lane & 15);
        af[i] = *(const short8*)(sA[cur] + r * 128 + (kfb ^ ((r & 7) << 4)));
      }
      #pragma unroll
      for (int j = 0; j < 2; ++j) {
        const int r = wn + j * 16 + (lane & 15);
        const int off = r * 128 + (kfb ^ ((r & 7) << 4));
        bg[j] = *(const short8*)(sBg[cur] + off);
        bu[j] = *(const short8*)(sBu[cur] + off);
      }
      #pragma unroll
      for (int i = 0; i < 4; ++i)
        #pragma unroll
        for (int j = 0; j < 2; ++j) {
          accg[i][j] = __builtin_amdgcn_mfma_f32_16x16x32_bf16(af[i], bg[j], accg[i][j], 0, 0, 0);
          accu[i][j] = __builtin_amdgcn_mfma_f32_16x16x32_bf16(af[i], bu[j], accu[i][j], 0, 0, 0);
        }
    }
    __builtin_amdgcn_s_barrier();
  }
#undef K1_STAGE

  unsigned short* ab = act + (size_t)e * T_TOK * INT_;
  #pragma unroll
  for (int i = 0; i < 4; ++i) {
    #pragma unroll
    for (int r = 0; r < 4; ++r) {
      const int slot = t0 + wm + i * 16 + ((lane >> 4) << 2) + r;
      if (slot < cnt) {
        #pragma unroll
        for (int j = 0; j < 2; ++j) {
          const int col = n0 + wn + j * 16 + (lane & 15);
          const float g = accg[i][j][r];
          const float u = accu[i][j][r];
          const float s = u * g / (1.f + __expf(-g));
          ab[(size_t)slot * INT_ + col] = __builtin_bit_cast(unsigned short, (__bf16)s);
        }
      }
    }
  }
}

// ---------------- Kernel 2: out += act[e] @ wdT[e]^T ------------------------
// R12 version verbatim (no setprio): 256 thr, M=128 N=128, K split 4-way,
// 2-buf counted vmcnt(8), 2 blocks/CU.
__global__ __launch_bounds__(256, 2)
void k2_down(const unsigned short* __restrict__ act,   // [e][T][INT_] bf16
             const unsigned short* __restrict__ wdT,   // [e][1024][4096] bf16
             float* __restrict__ out)
{
  const int e   = blockIdx.z;
  const int cnt = g_cnt[e];
  const int mt  = blockIdx.y >> 2;
  const int ks4 = blockIdx.y & 3;
  const int t0  = mt * 128;
  if (t0 >= cnt) return;

  __shared__ char sA[2][128 * 128];    // 32 KB
  __shared__ char sB[2][128 * 128];    // 32 KB

  const int nt   = blockIdx.x;
  const int tid  = threadIdx.x;
  const int lane = tid & 63;
  const int wv   = tid >> 6;           // 0..3
  const int wm   = (wv >> 1) * 64;
  const int wn   = (wv & 1) * 64;
  const int n0   = nt * 128;

  const unsigned short* ab = act + (size_t)e * T_TOK * INT_;
  const unsigned short* wb = wdT + (size_t)e * HID * INT_ + (size_t)n0 * INT_;

  f32x4 acc[4][4];
  #pragma unroll
  for (int i = 0; i < 4; ++i)
    #pragma unroll
    for (int j = 0; j < 4; ++j) acc[i][j] = (f32x4){0.f, 0.f, 0.f, 0.f};

  const int drow  = lane >> 3;
  const int dchk8 = (((lane & 7) ^ drow) << 3);
  const int kbeg  = ks4 * (INT_ / 4);

#define K2_STAGE(B, KT)                                                        \
  do {                                                                         \
    _Pragma("unroll")                                                          \
    for (int s_ = 0; s_ < 4; ++s_) {                                           \
      const int rb_ = (s_ * 4 + wv) * 8;                                       \
      GL16(ab + (size_t)(t0 + rb_ + drow) * INT_ + (KT) + dchk8, sA[B] + rb_ * 128); \
      GL16(wb + (size_t)(rb_ + drow) * INT_ + (KT) + dchk8, sB[B] + rb_ * 128);      \
    }                                                                          \
  } while (0)

  K2_STAGE(0, kbeg);

  #pragma unroll
  for (int t = 0; t < 16; ++t) {
    const int cur = t & 1;
    if (t < 15) K2_STAGE(cur ^ 1, kbeg + (t + 1) * 64);
    if (t < 15) asm volatile("s_waitcnt vmcnt(8)" ::: "memory");
    else        asm volatile("s_waitcnt vmcnt(0)" ::: "memory");
    __builtin_amdgcn_s_barrier();
    __builtin_amdgcn_sched_barrier(0);
    #pragma unroll
    for (int ks = 0; ks < 2; ++ks) {
      const int kfb = ks * 64 + ((lane >> 4) << 4);
      short8 af[4], bf[4];
      #pragma unroll
      for (int i = 0; i < 4; ++i) {
        const int r = wm + i * 16 + (lane & 15);
        af[i] = *(const short8*)(sA[cur] + r * 128 + (kfb ^ ((r & 7) << 4)));
      }
      #pragma unroll
      for (int j = 0; j < 4; ++j) {
        const int r = wn + j * 16 + (lane & 15);
        bf[j] = *(const short8*)(sB[cur] + r * 128 + (kfb ^ ((r & 7) << 4)));
      }
      #pragma unroll
      for (int i = 0; i < 4; ++i)
        #pragma unroll
        for (int j = 0; j < 4; ++j)
          acc[i][j] = __builtin_amdgcn_mfma_f32_16x16x32_bf16(af[i], bf[j], acc[i][j], 0, 0, 0);
    }
    __builtin_amdgcn_s_barrier();
  }
#undef K2_STAGE

  #pragma unroll
  for (int i = 0; i < 4; ++i) {
    #pragma unroll
    for (int r = 0; r < 4; ++r) {
      const int slot = t0 + wm + i * 16 + ((lane >> 4) << 2) + r;
      if (slot < cnt) {
        const int token = g_tok[e][slot];
        #pragma unroll
        for (int j = 0; j < 4; ++j) {
          const int col = n0 + wn + j * 16 + (lane & 15);
          atomicAdd(out + (size_t)token * HID + col, acc[i][j][r]);
        }
      }
    }
  }
}

extern "C" void kernel_launch(void* const* d_in, const int* in_sizes, int n_in,
                              void* d_out, int out_size, void* d_ws, size_t ws_size,
                              hipStream_t stream) {
  const float* x   = (const float*)d_in[0];
  const int*   idx = (const int*)d_in[1];
  const float* wgu = (const float*)d_in[2];
  const float* wd  = (const float*)d_in[3];
  float* out = (float*)d_out;

  // workspace layout (bytes):
  // act   @ 0          : 67,108,864
  // xb16  @ 67108864   :  2,097,152
  // wguT  @ 69206016   : 134,217,728
  // wdT   @ 203423744  : 67,108,864   (total ~258 MiB)
  char* ws = (char*)d_ws;
  unsigned short* act  = (unsigned short*)(ws);
  unsigned short* xb16 = (unsigned short*)(ws + 67108864);
  unsigned short* wguT = (unsigned short*)(ws + 69206016);
  unsigned short* wdT  = (unsigned short*)(ws + 203423744);

  hipMemsetAsync(d_out, 0, (size_t)out_size * sizeof(float), stream);

  k0_compact<<<1, 512, 0, stream>>>(idx);
  cvt_x<<<T_TOK * HID / (256 * 8), 256, 0, stream>>>(x, xb16);
  cvt_T<<<dim3(8192 / 64, 1024 / 64, NE), 256, 0, stream>>>(wgu, wguT, 1024, 8192);
  cvt_T<<<dim3(1024 / 64, 4096 / 64, NE), 256, 0, stream>>>(wd, wdT, 4096, 1024);

  dim3 g1(INT_ / 64, T_TOK / 128, NE);         // (64, 8, 8)
  k1_gateup<<<g1, dim3(256), 0, stream>>>(xb16, wguT, act);

  dim3 g2(HID / 128, (T_TOK / 128) * 4, NE);   // (8, 32, 8) — y = mt*4|ks
  k2_down<<<g2, dim3(256), 0, stream>>>(act, wdT, out);
}

// Round 16
// 319.322 us; speedup vs baseline: 1.1783x; 1.0462x over previous
//
#include <hip/hip_runtime.h>
#include <hip/hip_bf16.h>
#include <stdint.h>

#define T_TOK 1024
#define HID   1024
#define INT_  4096
#define NE    8

typedef __attribute__((ext_vector_type(4))) float f32x4;
typedef __attribute__((ext_vector_type(8))) short short8;

__device__ int g_tok[NE][T_TOK];
__device__ int g_cnt[NE];

__device__ __forceinline__ uint32_t pack2bf(float a, float b) {
  unsigned short ua = __builtin_bit_cast(unsigned short, (__bf16)a);
  unsigned short ub = __builtin_bit_cast(unsigned short, (__bf16)b);
  return (uint32_t)ua | ((uint32_t)ub << 16);
}

// global_load_lds: per-lane global src, wave-uniform LDS base (HW adds lane*16)
#define GL16(gsrc, ldst)                                                       \
  __builtin_amdgcn_global_load_lds(                                            \
      (const __attribute__((address_space(1))) void*)(gsrc),                   \
      (__attribute__((address_space(3))) void*)(ldst), 16, 0, 0)

// ---------------- Kernel 0: per-expert token compaction ---------------------
__global__ void k0_compact(const int* __restrict__ mask)  // [T_TOK][NE]
{
  const int w    = threadIdx.x >> 6;
  const int lane = threadIdx.x & 63;
  if (w >= NE) return;
  const unsigned long long ltmask = (1ull << lane) - 1ull;
  int base = 0;
  #pragma unroll
  for (int c = 0; c < T_TOK / 64; ++c) {
    const int t = c * 64 + lane;
    const bool pred = mask[t * NE + w] != 0;
    const unsigned long long bal = __ballot(pred);
    if (pred) g_tok[w][base + __popcll(bal & ltmask)] = t;
    base += __popcll(bal);
  }
  if (lane == 0) g_cnt[w] = base;
}

// ---------------- cvt_x: x f32 -> bf16 linear -------------------------------
__global__ void cvt_x(const float* __restrict__ xin, unsigned short* __restrict__ xout)
{
  const int i = (blockIdx.x * 256 + threadIdx.x) * 8;
  f32x4 a = *(const f32x4*)(xin + i);
  f32x4 b = *(const f32x4*)(xin + i + 4);
  uint4 u;
  u.x = pack2bf(a[0], a[1]); u.y = pack2bf(a[2], a[3]);
  u.z = pack2bf(b[0], b[1]); u.w = pack2bf(b[2], b[3]);
  *(uint4*)(xout + i) = u;
}

// ---------------- cvt_T: per-expert [R][C] f32 -> [C][R] bf16 ---------------
__global__ void cvt_T(const float* __restrict__ in, unsigned short* __restrict__ out,
                      int R, int C)
{
  __shared__ float tile[64][65];
  const int e  = blockIdx.z;
  const int c0 = blockIdx.x * 64;
  const int r0 = blockIdx.y * 64;
  const float*    ip = in  + (size_t)e * R * C;
  unsigned short* op = out + (size_t)e * R * C;
  const int t  = threadIdx.x;
  const int rr = t >> 4, c4 = (t & 15) * 4;
  #pragma unroll
  for (int s = 0; s < 4; ++s) {
    f32x4 v = *(const f32x4*)(ip + (size_t)(r0 + s * 16 + rr) * C + c0 + c4);
    tile[s * 16 + rr][c4 + 0] = v[0];
    tile[s * 16 + rr][c4 + 1] = v[1];
    tile[s * 16 + rr][c4 + 2] = v[2];
    tile[s * 16 + rr][c4 + 3] = v[3];
  }
  __syncthreads();
  const int c = t >> 2, rs = (t & 3) * 16;
  uint4 u0, u1;
  u0.x = pack2bf(tile[rs + 0][c],  tile[rs + 1][c]);
  u0.y = pack2bf(tile[rs + 2][c],  tile[rs + 3][c]);
  u0.z = pack2bf(tile[rs + 4][c],  tile[rs + 5][c]);
  u0.w = pack2bf(tile[rs + 6][c],  tile[rs + 7][c]);
  u1.x = pack2bf(tile[rs + 8][c],  tile[rs + 9][c]);
  u1.y = pack2bf(tile[rs + 10][c], tile[rs + 11][c]);
  u1.z = pack2bf(tile[rs + 12][c], tile[rs + 13][c]);
  u1.w = pack2bf(tile[rs + 14][c], tile[rs + 15][c]);
  unsigned short* orow = op + (size_t)(c0 + c) * R + r0 + rs;
  *(uint4*)(orow)     = u0;
  *(uint4*)(orow + 8) = u1;
}

// ---------------- Kernel 1: act[e,slot,i] = up * silu(gate) -----------------
// M=192 x N=64(g)+64(u), 256 thr (4 waves, 2m x 2n; wave m-extent 96),
// 2-buf 80 KB LDS -> exactly 2 blocks/CU (160 KiB). Counted vmcnt(10).
// Staged traffic 0.88 GB vs R15's 1.05 GB (-16%).
__global__ __launch_bounds__(256, 2)
void k1_gateup(const unsigned short* __restrict__ xb,    // [T][H] bf16
               const unsigned short* __restrict__ wguT,  // [e][8192][1024] bf16
               unsigned short* __restrict__ act)         // [e][T][INT_] bf16
{
  const int e   = blockIdx.z;
  const int cnt = g_cnt[e];
  const int mt  = blockIdx.y;
  const int t0  = mt * 192;
  if (t0 >= cnt) return;

  __shared__ char sA [2][192 * 128];   // 48 KB
  __shared__ char sBg[2][64 * 128];    // 16 KB
  __shared__ char sBu[2][64 * 128];    // 16 KB

  const int nt   = blockIdx.x;         // 0..63
  const int tid  = threadIdx.x;
  const int lane = tid & 63;
  const int wv   = tid >> 6;           // 0..3
  const int wm   = (wv >> 1) * 96;     // 0/96
  const int wn   = (wv & 1) * 32;      // 0/32
  const int n0   = nt * 64;

  const unsigned short* wg = wguT + (size_t)e * 8192 * HID + (size_t)n0 * HID;
  const unsigned short* wu = wg + (size_t)4096 * HID;

  f32x4 accg[6][2], accu[6][2];
  #pragma unroll
  for (int i = 0; i < 6; ++i)
    #pragma unroll
    for (int j = 0; j < 2; ++j) {
      accg[i][j] = (f32x4){0.f, 0.f, 0.f, 0.f};
      accu[i][j] = (f32x4){0.f, 0.f, 0.f, 0.f};
    }

  const int drow  = lane >> 3;                    // 0..7
  const int dchk8 = (((lane & 7) ^ drow) << 3);   // source-XOR chunk (rule #21)

  int tokA[6];
  #pragma unroll
  for (int s = 0; s < 6; ++s)
    tokA[s] = g_tok[e][t0 + (s * 4 + wv) * 8 + drow];   // rows 0..191

#define K1_STAGE(B, T_)                                                        \
  do {                                                                         \
    const int kt_ = (T_) * 64;                                                 \
    _Pragma("unroll")                                                          \
    for (int s_ = 0; s_ < 6; ++s_) {                                           \
      const int rb_ = (s_ * 4 + wv) * 8;                                       \
      GL16(xb + (size_t)tokA[s_] * HID + kt_ + dchk8, sA[B] + rb_ * 128);      \
    }                                                                          \
    _Pragma("unroll")                                                          \
    for (int s_ = 0; s_ < 2; ++s_) {                                           \
      const int rb_ = (s_ * 4 + wv) * 8;                                       \
      GL16(wg + (size_t)(rb_ + drow) * HID + kt_ + dchk8, sBg[B] + rb_ * 128); \
      GL16(wu + (size_t)(rb_ + drow) * HID + kt_ + dchk8, sBu[B] + rb_ * 128); \
    }                                                                          \
  } while (0)

  K1_STAGE(0, 0);

  #pragma unroll
  for (int t = 0; t < 16; ++t) {
    const int cur = t & 1;
    if (t < 15) K1_STAGE(cur ^ 1, t + 1);
    if (t < 15) asm volatile("s_waitcnt vmcnt(10)" ::: "memory");
    else        asm volatile("s_waitcnt vmcnt(0)" ::: "memory");
    __builtin_amdgcn_s_barrier();
    __builtin_amdgcn_sched_barrier(0);
    #pragma unroll
    for (int ks = 0; ks < 2; ++ks) {
      const int kfb = ks * 64 + ((lane >> 4) << 4);
      short8 af[6], bg[2], bu[2];
      #pragma unroll
      for (int i = 0; i < 6; ++i) {
        const int r = wm + i * 16 + (lane & 15);
        af[i] = *(const short8*)(sA[cur] + r * 128 + (kfb ^ ((r & 7) << 4)));
      }
      #pragma unroll
      for (int j = 0; j < 2; ++j) {
        const int r = wn + j * 16 + (lane & 15);
        const int off = r * 128 + (kfb ^ ((r & 7) << 4));
        bg[j] = *(const short8*)(sBg[cur] + off);
        bu[j] = *(const short8*)(sBu[cur] + off);
      }
      #pragma unroll
      for (int i = 0; i < 6; ++i)
        #pragma unroll
        for (int j = 0; j < 2; ++j) {
          accg[i][j] = __builtin_amdgcn_mfma_f32_16x16x32_bf16(af[i], bg[j], accg[i][j], 0, 0, 0);
          accu[i][j] = __builtin_amdgcn_mfma_f32_16x16x32_bf16(af[i], bu[j], accu[i][j], 0, 0, 0);
        }
    }
    __builtin_amdgcn_s_barrier();
  }
#undef K1_STAGE

  unsigned short* ab = act + (size_t)e * T_TOK * INT_;
  #pragma unroll
  for (int i = 0; i < 6; ++i) {
    #pragma unroll
    for (int r = 0; r < 4; ++r) {
      const int slot = t0 + wm + i * 16 + ((lane >> 4) << 2) + r;
      if (slot < cnt) {
        #pragma unroll
        for (int j = 0; j < 2; ++j) {
          const int col = n0 + wn + j * 16 + (lane & 15);
          const float g = accg[i][j][r];
          const float u = accu[i][j][r];
          const float s = u * g / (1.f + __expf(-g));
          ab[(size_t)slot * INT_ + col] = __builtin_bit_cast(unsigned short, (__bf16)s);
        }
      }
    }
  }
}

// ---------------- Kernel 2: out += act[e] @ wdT[e]^T ------------------------
// R12/R15 version verbatim: 256 thr, M=128 N=128, K split 4-way,
// 2-buf counted vmcnt(8), 2 blocks/CU.
__global__ __launch_bounds__(256, 2)
void k2_down(const unsigned short* __restrict__ act,   // [e][T][INT_] bf16
             const unsigned short* __restrict__ wdT,   // [e][1024][4096] bf16
             float* __restrict__ out)
{
  const int e   = blockIdx.z;
  const int cnt = g_cnt[e];
  const int mt  = blockIdx.y >> 2;
  const int ks4 = blockIdx.y & 3;
  const int t0  = mt * 128;
  if (t0 >= cnt) return;

  __shared__ char sA[2][128 * 128];    // 32 KB
  __shared__ char sB[2][128 * 128];    // 32 KB

  const int nt   = blockIdx.x;
  const int tid  = threadIdx.x;
  const int lane = tid & 63;
  const int wv   = tid >> 6;           // 0..3
  const int wm   = (wv >> 1) * 64;
  const int wn   = (wv & 1) * 64;
  const int n0   = nt * 128;

  const unsigned short* ab = act + (size_t)e * T_TOK * INT_;
  const unsigned short* wb = wdT + (size_t)e * HID * INT_ + (size_t)n0 * INT_;

  f32x4 acc[4][4];
  #pragma unroll
  for (int i = 0; i < 4; ++i)
    #pragma unroll
    for (int j = 0; j < 4; ++j) acc[i][j] = (f32x4){0.f, 0.f, 0.f, 0.f};

  const int drow  = lane >> 3;
  const int dchk8 = (((lane & 7) ^ drow) << 3);
  const int kbeg  = ks4 * (INT_ / 4);

#define K2_STAGE(B, KT)                                                        \
  do {                                                                         \
    _Pragma("unroll")                                                          \
    for (int s_ = 0; s_ < 4; ++s_) {                                           \
      const int rb_ = (s_ * 4 + wv) * 8;                                       \
      GL16(ab + (size_t)(t0 + rb_ + drow) * INT_ + (KT) + dchk8, sA[B] + rb_ * 128); \
      GL16(wb + (size_t)(rb_ + drow) * INT_ + (KT) + dchk8, sB[B] + rb_ * 128);      \
    }                                                                          \
  } while (0)

  K2_STAGE(0, kbeg);

  #pragma unroll
  for (int t = 0; t < 16; ++t) {
    const int cur = t & 1;
    if (t < 15) K2_STAGE(cur ^ 1, kbeg + (t + 1) * 64);
    if (t < 15) asm volatile("s_waitcnt vmcnt(8)" ::: "memory");
    else        asm volatile("s_waitcnt vmcnt(0)" ::: "memory");
    __builtin_amdgcn_s_barrier();
    __builtin_amdgcn_sched_barrier(0);
    #pragma unroll
    for (int ks = 0; ks < 2; ++ks) {
      const int kfb = ks * 64 + ((lane >> 4) << 4);
      short8 af[4], bf[4];
      #pragma unroll
      for (int i = 0; i < 4; ++i) {
        const int r = wm + i * 16 + (lane & 15);
        af[i] = *(const short8*)(sA[cur] + r * 128 + (kfb ^ ((r & 7) << 4)));
      }
      #pragma unroll
      for (int j = 0; j < 4; ++j) {
        const int r = wn + j * 16 + (lane & 15);
        bf[j] = *(const short8*)(sB[cur] + r * 128 + (kfb ^ ((r & 7) << 4)));
      }
      #pragma unroll
      for (int i = 0; i < 4; ++i)
        #pragma unroll
        for (int j = 0; j < 4; ++j)
          acc[i][j] = __builtin_amdgcn_mfma_f32_16x16x32_bf16(af[i], bf[j], acc[i][j], 0, 0, 0);
    }
    __builtin_amdgcn_s_barrier();
  }
#undef K2_STAGE

  #pragma unroll
  for (int i = 0; i < 4; ++i) {
    #pragma unroll
    for (int r = 0; r < 4; ++r) {
      const int slot = t0 + wm + i * 16 + ((lane >> 4) << 2) + r;
      if (slot < cnt) {
        const int token = g_tok[e][slot];
        #pragma unroll
        for (int j = 0; j < 4; ++j) {
          const int col = n0 + wn + j * 16 + (lane & 15);
          atomicAdd(out + (size_t)token * HID + col, acc[i][j][r]);
        }
      }
    }
  }
}

extern "C" void kernel_launch(void* const* d_in, const int* in_sizes, int n_in,
                              void* d_out, int out_size, void* d_ws, size_t ws_size,
                              hipStream_t stream) {
  const float* x   = (const float*)d_in[0];
  const int*   idx = (const int*)d_in[1];
  const float* wgu = (const float*)d_in[2];
  const float* wd  = (const float*)d_in[3];
  float* out = (float*)d_out;

  // workspace layout (bytes):
  // act   @ 0          : 67,108,864
  // xb16  @ 67108864   :  2,097,152
  // wguT  @ 69206016   : 134,217,728
  // wdT   @ 203423744  : 67,108,864   (total ~258 MiB)
  char* ws = (char*)d_ws;
  unsigned short* act  = (unsigned short*)(ws);
  unsigned short* xb16 = (unsigned short*)(ws + 67108864);
  unsigned short* wguT = (unsigned short*)(ws + 69206016);
  unsigned short* wdT  = (unsigned short*)(ws + 203423744);

  hipMemsetAsync(d_out, 0, (size_t)out_size * sizeof(float), stream);

  k0_compact<<<1, 512, 0, stream>>>(idx);
  cvt_x<<<T_TOK * HID / (256 * 8), 256, 0, stream>>>(x, xb16);
  cvt_T<<<dim3(8192 / 64, 1024 / 64, NE), 256, 0, stream>>>(wgu, wguT, 1024, 8192);
  cvt_T<<<dim3(1024 / 64, 4096 / 64, NE), 256, 0, stream>>>(wd, wdT, 4096, 1024);

  dim3 g1(INT_ / 64, 6, NE);                   // (64, 6, 8) — M=192 tiles
  k1_gateup<<<g1, dim3(256), 0, stream>>>(xb16, wguT, act);

  dim3 g2(HID / 128, (T_TOK / 128) * 4, NE);   // (8, 32, 8) — y = mt*4|ks
  k2_down<<<g2, dim3(256), 0, stream>>>(act, wdT, out);
}